// Round 12
// baseline (1880.385 us; speedup 1.0000x reference)
//
#include <hip/hip_runtime.h>
#include <hip/hip_bf16.h>
#include <stdint.h>

// RNN_75531294867647 on MI355X (gfx950)
// B=128 S=512 I=256 H=1024 O=256, fp32 in/out, LeakyReLU slope 0.01.
//
//   split:  x -> bf16 hi; Wi -> hi/lo bf16; Wh -> WA bf16 (cols 0:1024),
//           WB fp16 (cols 1024:2048)
//   gemm1:  xproj = LReLU(x @ Wi^T + bi) -> bf16, layout [S][B][H]  (128MB)
//   recur:  h <- LReLU(xproj_t @ WA^T + bh + h @ WB^T), 512 steps; h = single
//           fp16 plane. Round-11 core (best proven: phase U pre-poll, refills
//           pre-poll, ladder vmcnt(7-kc), L3-direct sc0 sc1). NEW sync:
//           (1) per-WAVE arrival (after own drain, BEFORE barrier B) -- the
//               publish no longer waits for wg-mates;
//           (2) per-wave producer-matched poll: stripe s=jw>>2 counts wave-
//               arrivals (16/step) of the 4 wgs producing k-slice s; wave kh
//               polls only stripes[kh] >= 16t (single dword). Barrier A
//               launders the 4 polls into the full-group guarantee before any
//               epilogue store; barrier B (after arrival) protects sT WAR.
//   out:    out = h @ Wo^T + bo (f32 VALU, tiny)

#define LRELU_SLOPE 0.01f

typedef unsigned short u16;
typedef __bf16 bf16x8 __attribute__((ext_vector_type(8)));
typedef _Float16 f16x8 __attribute__((ext_vector_type(8)));
typedef short  s16x8  __attribute__((ext_vector_type(8)));
typedef float  f32x4  __attribute__((ext_vector_type(4)));
typedef u16    u16x4  __attribute__((ext_vector_type(4)));
typedef uint32_t u32x2v __attribute__((ext_vector_type(2)));

__device__ __forceinline__ u16 f2bf(float f) {
  uint32_t u = __builtin_bit_cast(uint32_t, f);
  return (u16)((u + 0x7FFFu + ((u >> 16) & 1u)) >> 16);   // RNE
}
__device__ __forceinline__ float bf2f(u16 h) {
  uint32_t u = ((uint32_t)h) << 16;
  return __builtin_bit_cast(float, u);
}
__device__ __forceinline__ f32x4 mfma16(s16x8 a, s16x8 b, f32x4 c) {   // bf16
  return __builtin_amdgcn_mfma_f32_16x16x32_bf16(
      __builtin_bit_cast(bf16x8, a), __builtin_bit_cast(bf16x8, b), c, 0, 0, 0);
}
__device__ __forceinline__ f32x4 mfma16f(s16x8 a, s16x8 b, f32x4 c) {  // fp16
  return __builtin_amdgcn_mfma_f32_16x16x32_f16(
      __builtin_bit_cast(f16x8, a), __builtin_bit_cast(f16x8, b), c, 0, 0, 0);
}
__device__ __forceinline__ void gload_lds16(const void* g, void* l) {
  __builtin_amdgcn_global_load_lds(
      (const __attribute__((address_space(1))) void*)g,
      (__attribute__((address_space(3))) void*)l, 16, 0, 0);
}

// ---------------- fallback / split kernels -----------------------------------

__global__ void zero_out_k(float* __restrict__ out, int n) {
  int i = blockIdx.x * 256 + threadIdx.x;
  if (i < n) out[i] = 0.f;
}

__global__ void splitHi(const float* __restrict__ src, u16* __restrict__ hi, long n4) {
  long i = (long)blockIdx.x * 256 + threadIdx.x;
  if (i >= n4) return;
  float4 v = ((const float4*)src)[i];
  float a[4] = {v.x, v.y, v.z, v.w};
  u16x4 hv;
#pragma unroll
  for (int j = 0; j < 4; ++j) hv[j] = f2bf(a[j]);
  ((u16x4*)hi)[i] = hv;
}

__global__ void splitHiLo(const float* __restrict__ src, u16* __restrict__ hi,
                          u16* __restrict__ lo, long n4) {
  long i = (long)blockIdx.x * 256 + threadIdx.x;
  if (i >= n4) return;
  float4 v = ((const float4*)src)[i];
  float a[4] = {v.x, v.y, v.z, v.w};
  u16x4 hv, lv;
#pragma unroll
  for (int j = 0; j < 4; ++j) {
    u16 h = f2bf(a[j]);
    hv[j] = h;
    lv[j] = f2bf(a[j] - bf2f(h));
  }
  ((u16x4*)hi)[i] = hv;
  ((u16x4*)lo)[i] = lv;
}

// Wh [1024][2048] -> WAh = bf16(cols 0:1024), WBf = fp16(cols 1024:2048)
__global__ void split_wh(const float* __restrict__ Wh,
                         u16* __restrict__ WAh, u16* __restrict__ WBf) {
  long i4 = ((long)blockIdx.x * 256 + threadIdx.x) * 4;   // 1024*2048 elems
  int j = (int)(i4 >> 11), k2 = (int)(i4 & 2047);
  float4 v = *(const float4*)&Wh[i4];
  float a[4] = {v.x, v.y, v.z, v.w};
  if (k2 < 1024) {
    u16x4 hv;
#pragma unroll
    for (int q = 0; q < 4; ++q) hv[q] = f2bf(a[q]);
    *(u16x4*)&WAh[(long)j * 1024 + k2] = hv;
  } else {
    u16x4 fv;
#pragma unroll
    for (int q = 0; q < 4; ++q)
      fv[q] = __builtin_bit_cast(u16, (_Float16)a[q]);
    *(u16x4*)&WBf[(long)j * 1024 + (k2 - 1024)] = fv;
  }
}

// ---------------- gemm1: xproj = LReLU(x@Wi^T + bi) --------------------------

__global__ __launch_bounds__(256, 2)
void gemm_xproj(const u16* __restrict__ A, const u16* __restrict__ B0,
                const u16* __restrict__ B1, const float* __restrict__ bias,
                u16* __restrict__ outP) {
  __shared__ u16 sA[128 * 64], sB0[128 * 64], sB1[128 * 64];
  const int tid = threadIdx.x, wid = tid >> 6, lane = tid & 63;
  const int lrow = lane & 15, lgrp = lane >> 4;
  const int wm = wid >> 1, wn = wid & 1;
  const size_t m0 = (size_t)blockIdx.x * 128;
  const int n0 = blockIdx.y * 128;
  const int srow = tid >> 3, scol = (tid & 7) << 3;
  f32x4 acc[4][4] = {};

  for (int kt = 0; kt < 4; ++kt) {
    const int kph = kt << 6;
    __syncthreads();
#pragma unroll
    for (int sh = 0; sh < 4; ++sh) {
      const int r = sh * 32 + srow;
      gload_lds16(A  + (m0 + r) * 256 + kph + scol,          &sA [sh * 2048 + wid * 512]);
      gload_lds16(B0 + (size_t)(n0 + r) * 256 + kph + scol,  &sB0[sh * 2048 + wid * 512]);
      gload_lds16(B1 + (size_t)(n0 + r) * 256 + kph + scol,  &sB1[sh * 2048 + wid * 512]);
    }
    __syncthreads();
#pragma unroll
    for (int kk = 0; kk < 2; ++kk) {
      s16x8 bf0[4], bf1[4];
#pragma unroll
      for (int ni = 0; ni < 4; ++ni) {
        bf0[ni] = *(const s16x8*)&sB0[(wn * 64 + ni * 16 + lrow) * 64 + kk * 32 + lgrp * 8];
        bf1[ni] = *(const s16x8*)&sB1[(wn * 64 + ni * 16 + lrow) * 64 + kk * 32 + lgrp * 8];
      }
#pragma unroll
      for (int mi = 0; mi < 4; ++mi) {
        const s16x8 af = *(const s16x8*)&sA[(wm * 64 + mi * 16 + lrow) * 64 + kk * 32 + lgrp * 8];
#pragma unroll
        for (int ni = 0; ni < 4; ++ni) {
          acc[mi][ni] = mfma16(af, bf0[ni], acc[mi][ni]);
          acc[mi][ni] = mfma16(af, bf1[ni], acc[mi][ni]);
        }
      }
    }
  }
#pragma unroll
  for (int mi = 0; mi < 4; ++mi)
#pragma unroll
    for (int ni = 0; ni < 4; ++ni) {
      const int col = n0 + wn * 64 + ni * 16 + lrow;
      const float bv = bias[col];
#pragma unroll
      for (int r = 0; r < 4; ++r) {
        const size_t row = m0 + wm * 64 + mi * 16 + lgrp * 4 + r;
        float v = acc[mi][ni][r] + bv;
        v = (v >= 0.f) ? v : LRELU_SLOPE * v;
        const size_t b = row >> 9, s = row & 511;
        outP[(s * 128 + b) * 1024 + col] = f2bf(v);
      }
    }
}

// ---------------- recurrence -------------------------------------------------
// grid 128, 256 thr, 1 wg/CU. wg: g = wg&7 (rows b0=16g..+16), jw = wg>>3
// (cols j0=64jw..+64). Waves = K-quarters kh. h = fp16, single plane.
// Stripes: stripes[g][s], s = jw>>2, count WAVE-arrivals of the 4 wgs owning
// cols [s*256, s*256+256) -- i.e. the producers of k-slice s. 16 arrivals per
// stripe per step; target 16t. Wave kh polls only stripes[kh].
// Safety: (h-WAR) epilogue stores happen after barrier A, which joins the 4
// waves' polls -> all 64 wave-arrivals of the group >= t (all step t-1 ladders
// done). (sT WAR) barrier B after arrival, before next sT write. (publish)
// arrival after per-wave vmcnt(0) -> own h stores are L3-visible.

__global__ __launch_bounds__(256, 1)
void recur(const u16* __restrict__ WAh, const u16* __restrict__ WBf,
           const u16* __restrict__ xproj, const float* __restrict__ bh,
           u16* __restrict__ h0, u16* __restrict__ h1,
           unsigned* __restrict__ cnt) {
  __shared__ __align__(16) u16 sWB[64 * 1024];     // 128 KB (fp16)
  __shared__ __align__(16) float sT[4][16][68];    // padded for f32x4 reads
  const int tid = threadIdx.x, wid = tid >> 6, lane = tid & 63;
  const int lrow = lane & 15, lgrp = lane >> 4;
  const int kh = wid;                     // K-quarter
  const int wg = blockIdx.x, g = wg & 7, jw = wg >> 3;
  const int b0 = g * 16, j0 = jw * 64;

  // WB slice rows j0..j0+64, 16B-granule XOR swizzle (slot = s ^ (r&7))
  for (int i = tid; i < 64 * 128; i += 256) {
    const int r = i >> 7, s = i & 127, sg = s ^ (r & 7);
    *(s16x8*)&sWB[(size_t)i * 8] = *(const s16x8*)&WBf[(((size_t)(j0 + r)) << 10) + sg * 8];
  }

  // epilogue constants: thread -> (row er, 4 cols at ec4) = 8B fp16 store
  const int er = tid >> 4;
  const int ec4 = (tid & 15) * 4;
  const f32x4 bj4 = *(const f32x4*)&bh[j0 + ec4];

  unsigned* stripes = cnt + 64 + g * 64;      // 4 stripe counters / group
  unsigned* arr = stripes + (jw >> 2);        // arrival: producer stripe
  const unsigned* pollp = stripes + kh;       // poll: my k-slice's producers

  const size_t rowoff = (((size_t)(b0 + lrow)) << 10) + kh * 256 + lgrp * 8;
  const u16* waL = WAh + (((size_t)(j0 + lrow)) << 10) + kh * 256 + lgrp * 8;

  // prologue: xbuf <- xproj_0
  s16x8 xbuf[8];
#pragma unroll
  for (int kc = 0; kc < 8; ++kc)
    asm volatile("global_load_dwordx4 %0, %1, off"
                 : "=&v"(xbuf[kc]) : "v"(xproj + rowoff + kc * 32));
  asm volatile("s_waitcnt vmcnt(0)" ::: "memory");
  __syncthreads();                        // also covers LDS WB fill

  for (int t = 0; t < 512; ++t) {
    const u16* hp = ((t & 1) ? h1 : h0) + rowoff;
    u16* oh = (t & 1) ? h0 : h1;

    // ---- phase U: acc = xproj_t @ WA^T (pre-poll; hides under skew) ----
    f32x4 acc[4] = {{0.f,0.f,0.f,0.f},{0.f,0.f,0.f,0.f},{0.f,0.f,0.f,0.f},{0.f,0.f,0.f,0.f}};
#pragma unroll
    for (int n = 0; n < 4; ++n) {
#pragma unroll
      for (int kc = 0; kc < 8; ++kc) {
        const s16x8 wa = *(const s16x8*)(waL + ((size_t)n << 14) + kc * 32);
        acc[n] = mfma16(xbuf[kc], wa, acc[n]);
      }
    }

    // ---- refill xbuf for t+1 (pre-poll; completes during poll + phase H) ----
    {
      const int tn = (t < 511) ? t + 1 : 511;
      const u16* xnext = xproj + (((size_t)tn) << 17) + rowoff;
#pragma unroll
      for (int kc = 0; kc < 8; ++kc)
        asm volatile("global_load_dwordx4 %0, %1, off"
                     : "=&v"(xbuf[kc]) : "v"(xnext + kc * 32));
    }

    // ---- per-wave poll: my 4 producer wgs (16 wave-arrivals) reached t ----
    if (t) {
      const unsigned target = (unsigned)t * 16u;
      unsigned c;
      while (1) {
        asm volatile("global_load_dword %0, %1, off sc0 sc1\n\ts_waitcnt vmcnt(0)"
                     : "=&v"(c) : "v"(pollp) : "memory");
        if (c >= target) break;
        __builtin_amdgcn_s_sleep(1);
      }
    }
    __builtin_amdgcn_sched_barrier(0);

    // ---- phase H: 8 h-loads; queue = [8 refills][8 h]; ladder vmcnt(7-kc) ----
    s16x8 hb[8];
#pragma unroll
    for (int kc = 0; kc < 8; ++kc)
      asm volatile("global_load_dwordx4 %0, %1, off sc0 sc1"
                   : "=&v"(hb[kc]) : "v"(hp + kc * 32));
#pragma unroll
    for (int kc = 0; kc < 8; ++kc) {
      switch (kc) {
        case 0: asm volatile("s_waitcnt vmcnt(7)" ::: "memory"); break;
        case 1: asm volatile("s_waitcnt vmcnt(6)" ::: "memory"); break;
        case 2: asm volatile("s_waitcnt vmcnt(5)" ::: "memory"); break;
        case 3: asm volatile("s_waitcnt vmcnt(4)" ::: "memory"); break;
        case 4: asm volatile("s_waitcnt vmcnt(3)" ::: "memory"); break;
        case 5: asm volatile("s_waitcnt vmcnt(2)" ::: "memory"); break;
        case 6: asm volatile("s_waitcnt vmcnt(1)" ::: "memory"); break;
        default: asm volatile("s_waitcnt vmcnt(0)" ::: "memory"); break;
      }
      __builtin_amdgcn_sched_barrier(0);
      const int ka = kh * 32 + kc * 4 + lgrp;
#pragma unroll
      for (int n = 0; n < 4; ++n) {
        const int wr = n * 16 + lrow;
        const s16x8 wb = *(const s16x8*)&sWB[((size_t)wr << 10) + (size_t)((ka ^ (wr & 7)) << 3)];
        acc[n] = mfma16f(hb[kc], wb, acc[n]);
      }
    }

    // ---- partials -> sT ----
#pragma unroll
    for (int n = 0; n < 4; ++n)
#pragma unroll
      for (int r = 0; r < 4; ++r)
        sT[kh][lgrp * 4 + r][n * 16 + lrow] = acc[n][r];
    __syncthreads();                      // barrier A: partials visible AND
                                          // all 4 waves' polls passed (h-WAR)

    // ---- epilogue: reduce quarters, bias, LReLU, fp16 pack, one 8B store ----
    {
      f32x4 v = *(const f32x4*)&sT[0][er][ec4];
      v += *(const f32x4*)&sT[1][er][ec4];
      v += *(const f32x4*)&sT[2][er][ec4];
      v += *(const f32x4*)&sT[3][er][ec4];
      v += bj4;
      u16 o[4];
#pragma unroll
      for (int j = 0; j < 4; ++j) {
        float x = v[j];
        x = (x >= 0.f) ? x : LRELU_SLOPE * x;
        o[j] = __builtin_bit_cast(u16, (_Float16)x);
      }
      u32x2v pk;
      pk[0] = (unsigned)o[0] | ((unsigned)o[1] << 16);
      pk[1] = (unsigned)o[2] | ((unsigned)o[3] << 16);
      u16* dst = oh + (((size_t)(b0 + er)) << 10) + j0 + ec4;
      asm volatile("global_store_dwordx2 %0, %1, off sc0 sc1"
                   :: "v"(dst), "v"(pk) : "memory");
    }
    // ---- per-wave publish: own stores drained -> arrival (pre-barrier) ----
    asm volatile("s_waitcnt vmcnt(0)" ::: "memory");
    if (lane == 0)
      __hip_atomic_fetch_add(arr, 1u, __ATOMIC_RELAXED, __HIP_MEMORY_SCOPE_AGENT);
    __syncthreads();                      // barrier B: sT WAR only
  }
}

// ---------------- output GEMM (tiny, f32 VALU) -------------------------------

__global__ __launch_bounds__(256)
void out_gemm(const u16* __restrict__ hh,
              const float* __restrict__ Wo, const float* __restrict__ bo,
              float* __restrict__ out) {
  __shared__ float hrow[1024];
  const int b = blockIdx.x, tid = threadIdx.x;
  for (int k = tid; k < 1024; k += 256)
    hrow[k] = (float)__builtin_bit_cast(_Float16, hh[((size_t)b << 10) + k]);
  __syncthreads();
  const float* wo = Wo + (size_t)tid * 1024;
  float s0 = 0.f, s1 = 0.f, s2 = 0.f, s3 = 0.f;
  for (int k = 0; k < 1024; k += 4) {
    s0 = fmaf(wo[k + 0], hrow[k + 0], s0);
    s1 = fmaf(wo[k + 1], hrow[k + 1], s1);
    s2 = fmaf(wo[k + 2], hrow[k + 2], s2);
    s3 = fmaf(wo[k + 3], hrow[k + 3], s3);
  }
  out[(size_t)b * 256 + tid] = s0 + s1 + s2 + s3 + bo[tid];
}

// ---------------- launch ------------------------------------------------------

extern "C" void kernel_launch(void* const* d_in, const int* in_sizes, int n_in,
                              void* d_out, int out_size, void* d_ws, size_t ws_size,
                              hipStream_t stream) {
  const float* x  = (const float*)d_in[0];
  const float* Wi = (const float*)d_in[1];
  const float* bi = (const float*)d_in[2];
  const float* Wh = (const float*)d_in[3];
  const float* bh = (const float*)d_in[4];
  const float* Wo = (const float*)d_in[5];
  const float* bo = (const float*)d_in[6];

  char* w = (char*)d_ws;
  size_t off = 0;
  auto alloc = [&](size_t bytes) -> void* {
    void* p = w + off;
    off = (off + bytes + 255) & ~(size_t)255;
    return p;
  };
  u16* xh  = (u16*)alloc(33554432ull);    // x hi          [65536,256]
  u16* ph  = (u16*)alloc(134217728ull);   // xproj bf16    [512][128][1024]
  u16* Wih = (u16*)alloc(524288ull);
  u16* Wil = (u16*)alloc(524288ull);
  u16* WAh = (u16*)alloc(2097152ull);     // Wh[:, :1024] bf16
  u16* WBf = (u16*)alloc(2097152ull);     // Wh[:, 1024:] fp16
  u16* h0  = (u16*)alloc(262144ull);      // h fp16, double buffer
  u16* h1  = (u16*)alloc(262144ull);
  unsigned* cnt = (unsigned*)alloc(16384ull);
  const size_t needed = off;              // ~174 MB

  if (ws_size < needed) {                 // diagnostic fallback
    zero_out_k<<<(out_size + 255) / 256, 256, 0, stream>>>((float*)d_out, out_size);
    return;
  }

  hipMemsetAsync(cnt, 0, 16384, stream);
  hipMemsetAsync(h0, 0, 262144, stream);  // h_0 = 0
  hipMemsetAsync(h1, 0, 262144, stream);

  splitHi  <<<16384, 256, 0, stream>>>(x, xh, 4194304);
  splitHiLo<<<256,   256, 0, stream>>>(Wi, Wih, Wil, 65536);
  split_wh <<<2048,  256, 0, stream>>>(Wh, WAh, WBf);

  gemm_xproj<<<dim3(512, 8), 256, 0, stream>>>(xh, Wih, Wil, bi, ph);

  recur<<<128, 256, 0, stream>>>(WAh, WBf, ph, bh, h0, h1, cnt);
  out_gemm<<<128, 256, 0, stream>>>(h0, Wo, bo, (float*)d_out);
}

// Round 13
// 1806.275 us; speedup vs baseline: 1.0410x; 1.0410x over previous
//
#include <hip/hip_runtime.h>
#include <hip/hip_bf16.h>
#include <stdint.h>

// RNN_75531294867647 on MI355X (gfx950) — FINAL (round-11 best-proven state)
// B=128 S=512 I=256 H=1024 O=256, fp32 in/out, LeakyReLU slope 0.01.
//
//   split:  x -> bf16 hi; Wi -> hi/lo bf16; Wh -> WA bf16 (cols 0:1024),
//           WB fp16 (cols 1024:2048)
//   gemm1:  xproj = LReLU(x @ Wi^T + bi) -> bf16, layout [S][B][H]  (128MB)
//   recur:  h <- LReLU(xproj_t @ WA^T + bh + h @ WB^T), 512 steps; h = single
//           fp16 plane (verified: absmax unchanged vs hi/lo bf16 pair).
//           Schedule (best proven, r11 = 3.3 us/step): phase U pre-poll (hides
//           under rendezvous skew, polls hit first-try), xbuf refills pre-poll,
//           8 h-loads post-poll with ladder vmcnt(7-kc); striped arrival
//           (atomic add, 4 stripes/group) + dwordx4 min-of-4 poll; ALL
//           exchange L3-direct (sc0 sc1 — L2-scope variants hung, abandoned);
//           grid 128, 1 wg/CU, g=wg&7 groups (one XCD/group round-robin).
//           Measured floor: latency/sync-bound (MfmaUtil ~6.5%, HBM ~2%) —
//           NOT a HW roofline; protocol-family refinements exhausted
//           (r6/r9/r12 neutral, r7/r10 regressions).
//   out:    out = h @ Wo^T + bo (f32 VALU, tiny)

#define LRELU_SLOPE 0.01f

typedef unsigned short u16;
typedef __bf16 bf16x8 __attribute__((ext_vector_type(8)));
typedef _Float16 f16x8 __attribute__((ext_vector_type(8)));
typedef short  s16x8  __attribute__((ext_vector_type(8)));
typedef float  f32x4  __attribute__((ext_vector_type(4)));
typedef u16    u16x4  __attribute__((ext_vector_type(4)));
typedef uint32_t u32x4v __attribute__((ext_vector_type(4)));
typedef uint32_t u32x2v __attribute__((ext_vector_type(2)));

__device__ __forceinline__ u16 f2bf(float f) {
  uint32_t u = __builtin_bit_cast(uint32_t, f);
  return (u16)((u + 0x7FFFu + ((u >> 16) & 1u)) >> 16);   // RNE
}
__device__ __forceinline__ float bf2f(u16 h) {
  uint32_t u = ((uint32_t)h) << 16;
  return __builtin_bit_cast(float, u);
}
__device__ __forceinline__ f32x4 mfma16(s16x8 a, s16x8 b, f32x4 c) {   // bf16
  return __builtin_amdgcn_mfma_f32_16x16x32_bf16(
      __builtin_bit_cast(bf16x8, a), __builtin_bit_cast(bf16x8, b), c, 0, 0, 0);
}
__device__ __forceinline__ f32x4 mfma16f(s16x8 a, s16x8 b, f32x4 c) {  // fp16
  return __builtin_amdgcn_mfma_f32_16x16x32_f16(
      __builtin_bit_cast(f16x8, a), __builtin_bit_cast(f16x8, b), c, 0, 0, 0);
}
__device__ __forceinline__ void gload_lds16(const void* g, void* l) {
  __builtin_amdgcn_global_load_lds(
      (const __attribute__((address_space(1))) void*)g,
      (__attribute__((address_space(3))) void*)l, 16, 0, 0);
}

// ---------------- fallback / split kernels -----------------------------------

__global__ void zero_out_k(float* __restrict__ out, int n) {
  int i = blockIdx.x * 256 + threadIdx.x;
  if (i < n) out[i] = 0.f;
}

__global__ void splitHi(const float* __restrict__ src, u16* __restrict__ hi, long n4) {
  long i = (long)blockIdx.x * 256 + threadIdx.x;
  if (i >= n4) return;
  float4 v = ((const float4*)src)[i];
  float a[4] = {v.x, v.y, v.z, v.w};
  u16x4 hv;
#pragma unroll
  for (int j = 0; j < 4; ++j) hv[j] = f2bf(a[j]);
  ((u16x4*)hi)[i] = hv;
}

__global__ void splitHiLo(const float* __restrict__ src, u16* __restrict__ hi,
                          u16* __restrict__ lo, long n4) {
  long i = (long)blockIdx.x * 256 + threadIdx.x;
  if (i >= n4) return;
  float4 v = ((const float4*)src)[i];
  float a[4] = {v.x, v.y, v.z, v.w};
  u16x4 hv, lv;
#pragma unroll
  for (int j = 0; j < 4; ++j) {
    u16 h = f2bf(a[j]);
    hv[j] = h;
    lv[j] = f2bf(a[j] - bf2f(h));
  }
  ((u16x4*)hi)[i] = hv;
  ((u16x4*)lo)[i] = lv;
}

// Wh [1024][2048] -> WAh = bf16(cols 0:1024), WBf = fp16(cols 1024:2048)
__global__ void split_wh(const float* __restrict__ Wh,
                         u16* __restrict__ WAh, u16* __restrict__ WBf) {
  long i4 = ((long)blockIdx.x * 256 + threadIdx.x) * 4;   // 1024*2048 elems
  int j = (int)(i4 >> 11), k2 = (int)(i4 & 2047);
  float4 v = *(const float4*)&Wh[i4];
  float a[4] = {v.x, v.y, v.z, v.w};
  if (k2 < 1024) {
    u16x4 hv;
#pragma unroll
    for (int q = 0; q < 4; ++q) hv[q] = f2bf(a[q]);
    *(u16x4*)&WAh[(long)j * 1024 + k2] = hv;
  } else {
    u16x4 fv;
#pragma unroll
    for (int q = 0; q < 4; ++q)
      fv[q] = __builtin_bit_cast(u16, (_Float16)a[q]);
    *(u16x4*)&WBf[(long)j * 1024 + (k2 - 1024)] = fv;
  }
}

// ---------------- gemm1: xproj = LReLU(x@Wi^T + bi) --------------------------

__global__ __launch_bounds__(256, 2)
void gemm_xproj(const u16* __restrict__ A, const u16* __restrict__ B0,
                const u16* __restrict__ B1, const float* __restrict__ bias,
                u16* __restrict__ outP) {
  __shared__ u16 sA[128 * 64], sB0[128 * 64], sB1[128 * 64];
  const int tid = threadIdx.x, wid = tid >> 6, lane = tid & 63;
  const int lrow = lane & 15, lgrp = lane >> 4;
  const int wm = wid >> 1, wn = wid & 1;
  const size_t m0 = (size_t)blockIdx.x * 128;
  const int n0 = blockIdx.y * 128;
  const int srow = tid >> 3, scol = (tid & 7) << 3;
  f32x4 acc[4][4] = {};

  for (int kt = 0; kt < 4; ++kt) {
    const int kph = kt << 6;
    __syncthreads();
#pragma unroll
    for (int sh = 0; sh < 4; ++sh) {
      const int r = sh * 32 + srow;
      gload_lds16(A  + (m0 + r) * 256 + kph + scol,          &sA [sh * 2048 + wid * 512]);
      gload_lds16(B0 + (size_t)(n0 + r) * 256 + kph + scol,  &sB0[sh * 2048 + wid * 512]);
      gload_lds16(B1 + (size_t)(n0 + r) * 256 + kph + scol,  &sB1[sh * 2048 + wid * 512]);
    }
    __syncthreads();
#pragma unroll
    for (int kk = 0; kk < 2; ++kk) {
      s16x8 bf0[4], bf1[4];
#pragma unroll
      for (int ni = 0; ni < 4; ++ni) {
        bf0[ni] = *(const s16x8*)&sB0[(wn * 64 + ni * 16 + lrow) * 64 + kk * 32 + lgrp * 8];
        bf1[ni] = *(const s16x8*)&sB1[(wn * 64 + ni * 16 + lrow) * 64 + kk * 32 + lgrp * 8];
      }
#pragma unroll
      for (int mi = 0; mi < 4; ++mi) {
        const s16x8 af = *(const s16x8*)&sA[(wm * 64 + mi * 16 + lrow) * 64 + kk * 32 + lgrp * 8];
#pragma unroll
        for (int ni = 0; ni < 4; ++ni) {
          acc[mi][ni] = mfma16(af, bf0[ni], acc[mi][ni]);
          acc[mi][ni] = mfma16(af, bf1[ni], acc[mi][ni]);
        }
      }
    }
  }
#pragma unroll
  for (int mi = 0; mi < 4; ++mi)
#pragma unroll
    for (int ni = 0; ni < 4; ++ni) {
      const int col = n0 + wn * 64 + ni * 16 + lrow;
      const float bv = bias[col];
#pragma unroll
      for (int r = 0; r < 4; ++r) {
        const size_t row = m0 + wm * 64 + mi * 16 + lgrp * 4 + r;
        float v = acc[mi][ni][r] + bv;
        v = (v >= 0.f) ? v : LRELU_SLOPE * v;
        const size_t b = row >> 9, s = row & 511;
        outP[(s * 128 + b) * 1024 + col] = f2bf(v);
      }
    }
}

// ---------------- recurrence (round-9 schedule, fp16 h/WB) -------------------
// grid 128, 256 thr, 1 wg/CU. wg: g = wg&7 (rows b0=16g..+16), jw = wg>>3
// (cols j0=64jw..+64). Waves = K-quarters kh. h = fp16, single plane.
// Per step t:
//   phase U (pre-poll): acc = xproj_t @ WA^T  (xbuf regs, WA from L2)
//   refill xbuf <- xproj_{t+1} (pre-poll; completes during poll + phase H)
//   poll: striped counters, dwordx4 min-of-4 >= 4t, s_sleep(1)
//   phase H: 8 h-loads (sc0 sc1); queue = [8 refills][8 h]; h[kc] retired at
//            vmcnt(7-kc); acc += h @ WB^T (fp16 MFMA)
//   sT reduce -> barrier A -> epilogue (fp16 pack, one 8B store) -> vmcnt(0)
//   -> barrier B -> tid0 striped arrival (relaxed atomic add).
// WAR safety: poll at t guarantees all 16 wgs finished t-1 before overwrite.

__global__ __launch_bounds__(256, 1)
void recur(const u16* __restrict__ WAh, const u16* __restrict__ WBf,
           const u16* __restrict__ xproj, const float* __restrict__ bh,
           u16* __restrict__ h0, u16* __restrict__ h1,
           unsigned* __restrict__ cnt) {
  __shared__ __align__(16) u16 sWB[64 * 1024];     // 128 KB (fp16)
  __shared__ __align__(16) float sT[4][16][68];    // padded for f32x4 reads
  const int tid = threadIdx.x, wid = tid >> 6, lane = tid & 63;
  const int lrow = lane & 15, lgrp = lane >> 4;
  const int kh = wid;                     // K-quarter
  const int wg = blockIdx.x, g = wg & 7, jw = wg >> 3;
  const int b0 = g * 16, j0 = jw * 64;

  // WB slice rows j0..j0+64, 16B-granule XOR swizzle (slot = s ^ (r&7))
  for (int i = tid; i < 64 * 128; i += 256) {
    const int r = i >> 7, s = i & 127, sg = s ^ (r & 7);
    *(s16x8*)&sWB[(size_t)i * 8] = *(const s16x8*)&WBf[(((size_t)(j0 + r)) << 10) + sg * 8];
  }

  // epilogue constants: thread -> (row er, 4 cols at ec4) = 8B fp16 store
  const int er = tid >> 4;
  const int ec4 = (tid & 15) * 4;
  const f32x4 bj4 = *(const f32x4*)&bh[j0 + ec4];

  unsigned* stripes = cnt + 64 + g * 64;  // 4 stripe counters, one 16B line
  unsigned* mystripe = stripes + (jw & 3);

  const size_t rowoff = (((size_t)(b0 + lrow)) << 10) + kh * 256 + lgrp * 8;
  const u16* waL = WAh + (((size_t)(j0 + lrow)) << 10) + kh * 256 + lgrp * 8;

  // prologue: xbuf <- xproj_0
  s16x8 xbuf[8];
#pragma unroll
  for (int kc = 0; kc < 8; ++kc)
    asm volatile("global_load_dwordx4 %0, %1, off"
                 : "=&v"(xbuf[kc]) : "v"(xproj + rowoff + kc * 32));
  asm volatile("s_waitcnt vmcnt(0)" ::: "memory");
  __syncthreads();                        // also covers LDS WB fill

  for (int t = 0; t < 512; ++t) {
    const u16* hp = ((t & 1) ? h1 : h0) + rowoff;
    u16* oh = (t & 1) ? h0 : h1;

    // ---- phase U: acc = xproj_t @ WA^T (pre-poll; hides under skew) ----
    f32x4 acc[4] = {{0.f,0.f,0.f,0.f},{0.f,0.f,0.f,0.f},{0.f,0.f,0.f,0.f},{0.f,0.f,0.f,0.f}};
#pragma unroll
    for (int n = 0; n < 4; ++n) {
#pragma unroll
      for (int kc = 0; kc < 8; ++kc) {
        const s16x8 wa = *(const s16x8*)(waL + ((size_t)n << 14) + kc * 32);
        acc[n] = mfma16(xbuf[kc], wa, acc[n]);
      }
    }

    // ---- refill xbuf for t+1 (pre-poll; completes during poll + phase H) ----
    {
      const int tn = (t < 511) ? t + 1 : 511;
      const u16* xnext = xproj + (((size_t)tn) << 17) + rowoff;
#pragma unroll
      for (int kc = 0; kc < 8; ++kc)
        asm volatile("global_load_dwordx4 %0, %1, off"
                     : "=&v"(xbuf[kc]) : "v"(xnext + kc * 32));
    }

    // ---- spin: h_t ready when every stripe reached 4t ----
    if (t) {
      const unsigned target = (unsigned)t * 4u;
      u32x4v f;
      while (1) {
        asm volatile("global_load_dwordx4 %0, %1, off sc0 sc1\n\ts_waitcnt vmcnt(0)"
                     : "=&v"(f) : "v"(stripes) : "memory");
        const unsigned m01 = f[0] < f[1] ? f[0] : f[1];
        const unsigned m23 = f[2] < f[3] ? f[2] : f[3];
        if ((m01 < m23 ? m01 : m23) >= target) break;
        __builtin_amdgcn_s_sleep(1);
      }
    }
    __builtin_amdgcn_sched_barrier(0);

    // ---- phase H: 8 h-loads; queue = [8 refills][8 h]; ladder vmcnt(7-kc) ----
    s16x8 hb[8];
#pragma unroll
    for (int kc = 0; kc < 8; ++kc)
      asm volatile("global_load_dwordx4 %0, %1, off sc0 sc1"
                   : "=&v"(hb[kc]) : "v"(hp + kc * 32));
#pragma unroll
    for (int kc = 0; kc < 8; ++kc) {
      switch (kc) {
        case 0: asm volatile("s_waitcnt vmcnt(7)" ::: "memory"); break;
        case 1: asm volatile("s_waitcnt vmcnt(6)" ::: "memory"); break;
        case 2: asm volatile("s_waitcnt vmcnt(5)" ::: "memory"); break;
        case 3: asm volatile("s_waitcnt vmcnt(4)" ::: "memory"); break;
        case 4: asm volatile("s_waitcnt vmcnt(3)" ::: "memory"); break;
        case 5: asm volatile("s_waitcnt vmcnt(2)" ::: "memory"); break;
        case 6: asm volatile("s_waitcnt vmcnt(1)" ::: "memory"); break;
        default: asm volatile("s_waitcnt vmcnt(0)" ::: "memory"); break;
      }
      __builtin_amdgcn_sched_barrier(0);
      const int ka = kh * 32 + kc * 4 + lgrp;
#pragma unroll
      for (int n = 0; n < 4; ++n) {
        const int wr = n * 16 + lrow;
        const s16x8 wb = *(const s16x8*)&sWB[((size_t)wr << 10) + (size_t)((ka ^ (wr & 7)) << 3)];
        acc[n] = mfma16f(hb[kc], wb, acc[n]);
      }
    }

    // ---- partials -> sT ----
#pragma unroll
    for (int n = 0; n < 4; ++n)
#pragma unroll
      for (int r = 0; r < 4; ++r)
        sT[kh][lgrp * 4 + r][n * 16 + lrow] = acc[n][r];
    __syncthreads();                      // barrier A: partials visible

    // ---- epilogue: reduce quarters, bias, LReLU, fp16 pack, one 8B store ----
    {
      f32x4 v = *(const f32x4*)&sT[0][er][ec4];
      v += *(const f32x4*)&sT[1][er][ec4];
      v += *(const f32x4*)&sT[2][er][ec4];
      v += *(const f32x4*)&sT[3][er][ec4];
      v += bj4;
      u16 o[4];
#pragma unroll
      for (int j = 0; j < 4; ++j) {
        float x = v[j];
        x = (x >= 0.f) ? x : LRELU_SLOPE * x;
        o[j] = __builtin_bit_cast(u16, (_Float16)x);
      }
      u32x2v pk;
      pk[0] = (unsigned)o[0] | ((unsigned)o[1] << 16);
      pk[1] = (unsigned)o[2] | ((unsigned)o[3] << 16);
      u16* dst = oh + (((size_t)(b0 + er)) << 10) + j0 + ec4;
      asm volatile("global_store_dwordx2 %0, %1, off sc0 sc1"
                   :: "v"(dst), "v"(pk) : "memory");
    }
    asm volatile("s_waitcnt vmcnt(0)" ::: "memory");  // h store drained
    __syncthreads();                      // barrier B: wg-wide drain + sT WAR
    if (tid == 0)
      __hip_atomic_fetch_add(mystripe, 1u, __ATOMIC_RELAXED, __HIP_MEMORY_SCOPE_AGENT);
  }
}

// ---------------- output GEMM (tiny, f32 VALU) -------------------------------

__global__ __launch_bounds__(256)
void out_gemm(const u16* __restrict__ hh,
              const float* __restrict__ Wo, const float* __restrict__ bo,
              float* __restrict__ out) {
  __shared__ float hrow[1024];
  const int b = blockIdx.x, tid = threadIdx.x;
  for (int k = tid; k < 1024; k += 256)
    hrow[k] = (float)__builtin_bit_cast(_Float16, hh[((size_t)b << 10) + k]);
  __syncthreads();
  const float* wo = Wo + (size_t)tid * 1024;
  float s0 = 0.f, s1 = 0.f, s2 = 0.f, s3 = 0.f;
  for (int k = 0; k < 1024; k += 4) {
    s0 = fmaf(wo[k + 0], hrow[k + 0], s0);
    s1 = fmaf(wo[k + 1], hrow[k + 1], s1);
    s2 = fmaf(wo[k + 2], hrow[k + 2], s2);
    s3 = fmaf(wo[k + 3], hrow[k + 3], s3);
  }
  out[(size_t)b * 256 + tid] = s0 + s1 + s2 + s3 + bo[tid];
}

// ---------------- launch ------------------------------------------------------

extern "C" void kernel_launch(void* const* d_in, const int* in_sizes, int n_in,
                              void* d_out, int out_size, void* d_ws, size_t ws_size,
                              hipStream_t stream) {
  const float* x  = (const float*)d_in[0];
  const float* Wi = (const float*)d_in[1];
  const float* bi = (const float*)d_in[2];
  const float* Wh = (const float*)d_in[3];
  const float* bh = (const float*)d_in[4];
  const float* Wo = (const float*)d_in[5];
  const float* bo = (const float*)d_in[6];

  char* w = (char*)d_ws;
  size_t off = 0;
  auto alloc = [&](size_t bytes) -> void* {
    void* p = w + off;
    off = (off + bytes + 255) & ~(size_t)255;
    return p;
  };
  u16* xh  = (u16*)alloc(33554432ull);    // x hi          [65536,256]
  u16* ph  = (u16*)alloc(134217728ull);   // xproj bf16    [512][128][1024]
  u16* Wih = (u16*)alloc(524288ull);
  u16* Wil = (u16*)alloc(524288ull);
  u16* WAh = (u16*)alloc(2097152ull);     // Wh[:, :1024] bf16
  u16* WBf = (u16*)alloc(2097152ull);     // Wh[:, 1024:] fp16
  u16* h0  = (u16*)alloc(262144ull);      // h fp16, double buffer
  u16* h1  = (u16*)alloc(262144ull);
  unsigned* cnt = (unsigned*)alloc(16384ull);
  const size_t needed = off;              // ~174 MB

  if (ws_size < needed) {                 // diagnostic fallback
    zero_out_k<<<(out_size + 255) / 256, 256, 0, stream>>>((float*)d_out, out_size);
    return;
  }

  hipMemsetAsync(cnt, 0, 16384, stream);
  hipMemsetAsync(h0, 0, 262144, stream);  // h_0 = 0
  hipMemsetAsync(h1, 0, 262144, stream);

  splitHi  <<<16384, 256, 0, stream>>>(x, xh, 4194304);
  splitHiLo<<<256,   256, 0, stream>>>(Wi, Wih, Wil, 65536);
  split_wh <<<2048,  256, 0, stream>>>(Wh, WAh, WBf);

  gemm_xproj<<<dim3(512, 8), 256, 0, stream>>>(xh, Wih, Wil, bi, ph);

  recur<<<128, 256, 0, stream>>>(WAh, WBf, ph, bh, h0, h1, cnt);
  out_gemm<<<128, 256, 0, stream>>>(h0, Wo, bo, (float*)d_out);
}